// Round 3
// baseline (215.111 us; speedup 1.0000x reference)
//
#include <hip/hip_runtime.h>

#define NN 25000
#define EE 400000
#define FIN 128
#define FE 16
#define CH 32
#define SLOPE 0.01f
#define PROJ_BLOCKS 391   // ceil(25000/64)
#define AUX_BLOCKS 64

typedef __attribute__((ext_vector_type(8))) short bf16x8;
typedef __attribute__((ext_vector_type(4))) float f32x4;

__device__ __forceinline__ float lrelu(float v) { return fmaxf(v, SLOPE * v); }

// float -> bf16 bits, round-to-nearest-even
__device__ __forceinline__ short f2bf(float f) {
    union { float f; unsigned u; } v; v.f = f;
    unsigned r = (v.u + 0x7fffu + ((v.u >> 16) & 1u)) >> 16;
    return (short)r;
}

// ---------------- Kernel 1: fused prep
// blocks [0, PROJ_BLOCKS): h = leaky(x @ W_in + b_in) via MFMA (64 nodes/block)
// blocks [PROJ_BLOCKS, +AUX): zero aggr; WtT = bf16(W_edge^T); ea_bf = bf16(ea)
__global__ void __launch_bounds__(256)
k_pre(const float* __restrict__ x, const float* __restrict__ W_in,
      const float* __restrict__ b_in, const float* __restrict__ ea,
      const float* __restrict__ W_edge,
      float* __restrict__ h, float* __restrict__ aggr,
      short* __restrict__ WtT, short* __restrict__ ea_bf) {
    __shared__ short Wt1[CH * 136];
    int tid = threadIdx.x;

    if (blockIdx.x >= PROJ_BLOCKS) {
        int t = (blockIdx.x - PROJ_BLOCKS) * 256 + tid;     // 0..16383
        // W_edge [16][1024] -> WtT[co][k] bf16
        { int co = t >> 4, k = t & 15; WtT[t] = f2bf(W_edge[k * 1024 + co]); }
        // zero aggr
        float4 z = make_float4(0.f, 0.f, 0.f, 0.f);
        for (int i = t; i < NN * CH / 4; i += AUX_BLOCKS * 256) ((float4*)aggr)[i] = z;
        // ea fp32 -> bf16 rows
        for (int e = t; e < EE; e += AUX_BLOCKS * 256) {
            const float4* p = (const float4*)(ea + (size_t)e * FE);
            float4 a0 = p[0], a1 = p[1], a2 = p[2], a3 = p[3];
            bf16x8 lo = (bf16x8){f2bf(a0.x), f2bf(a0.y), f2bf(a0.z), f2bf(a0.w),
                                 f2bf(a1.x), f2bf(a1.y), f2bf(a1.z), f2bf(a1.w)};
            bf16x8 hi = (bf16x8){f2bf(a2.x), f2bf(a2.y), f2bf(a2.z), f2bf(a2.w),
                                 f2bf(a3.x), f2bf(a3.y), f2bf(a3.z), f2bf(a3.w)};
            ((bf16x8*)(ea_bf + (size_t)e * FE))[0] = lo;
            ((bf16x8*)(ea_bf + (size_t)e * FE))[1] = hi;
        }
        return;
    }

    // ---- input projection ----
#pragma unroll
    for (int i = 0; i < 16; i++) {
        int id = tid + 256 * i;           // id = k*32 + c
        int k = id >> 5, c = id & 31;
        Wt1[c * 136 + k] = f2bf(W_in[id]);
    }
    __syncthreads();

    int wave = tid >> 6, lane = tid & 63;
    int n16 = lane & 15, quad = lane >> 4;
    int node0 = blockIdx.x * 64 + wave * 16;

    f32x4 D[2];
#pragma unroll
    for (int ch = 0; ch < 2; ch++) {
        float bb = b_in[ch * 16 + n16];
        D[ch] = (f32x4){bb, bb, bb, bb};
    }
    int arow = node0 + n16; if (arow >= NN) arow = NN - 1;
#pragma unroll
    for (int kb = 0; kb < 4; kb++) {
        const float4* xp = (const float4*)(x + (size_t)arow * FIN + kb * 32 + quad * 8);
        float4 xa = xp[0], xb = xp[1];
        bf16x8 A = (bf16x8){f2bf(xa.x), f2bf(xa.y), f2bf(xa.z), f2bf(xa.w),
                            f2bf(xb.x), f2bf(xb.y), f2bf(xb.z), f2bf(xb.w)};
#pragma unroll
        for (int ch = 0; ch < 2; ch++) {
            bf16x8 B = *(const bf16x8*)&Wt1[(ch * 16 + n16) * 136 + kb * 32 + quad * 8];
            D[ch] = __builtin_amdgcn_mfma_f32_16x16x32_bf16(A, B, D[ch], 0, 0, 0);
        }
    }
#pragma unroll
    for (int ch = 0; ch < 2; ch++)
#pragma unroll
        for (int r = 0; r < 4; r++) {
            int nn = node0 + quad * 4 + r;
            if (nn < NN) h[(size_t)nn * CH + ch * 16 + n16] = lrelu(D[ch][r]);
        }
}

// ---------------- Kernel 2: fused edge-NN (MFMA bf16) + matvec + scatter
__global__ void __launch_bounds__(256, 3)
k_edge(const short* __restrict__ WtT,    // [1024][16] bf16 (W_edge^T)
       const short* __restrict__ ea_bf,  // [EE][16] bf16
       const float* __restrict__ b_edge,
       const int* __restrict__ src,
       const int* __restrict__ dst,
       const float* __restrict__ h,
       float* __restrict__ aggr) {
    __shared__ short WtL[1024 * 16];   // 32 KB
    __shared__ float hsL[128 * 36];    // 18 KB, rows padded 32->36
    __shared__ short zslot[8];

    int tid = threadIdx.x;
    int e0 = blockIdx.x * 128;

    if (tid < 8) zslot[tid] = 0;
    // stage WtL: 2048 16B chunks, vector copy, no conversion
#pragma unroll
    for (int j = 0; j < 8; j++) {
        int idx = tid + 256 * j;
        ((uint4*)WtL)[idx] = ((const uint4*)WtT)[idx];
    }
    // stage h[src[e]] rows
    {
        int e = tid >> 1, half = tid & 1;
        int s = src[e0 + e];
        const float4* hp = (const float4*)(h + (size_t)s * CH + half * 16);
        float* wdst = &hsL[e * 36 + half * 16];
#pragma unroll
        for (int j = 0; j < 4; j++) *(float4*)(wdst + j * 4) = hp[j];
    }
    __syncthreads();

    int wave = tid >> 6, lane = tid & 63;
    int n16 = lane & 15, quad = lane >> 4;
    int t0 = wave * 32, t1 = t0 + 16;

    // A fragments direct from bf16 (quads 2,3 = zero K-pad)
    bf16x8 A0 = *(const bf16x8*)(ea_bf + (size_t)(e0 + t0 + n16) * FE + (quad & 1) * 8);
    bf16x8 A1 = *(const bf16x8*)(ea_bf + (size_t)(e0 + t1 + n16) * FE + (quad & 1) * 8);
    if (quad >= 2) { A0 = (bf16x8){0,0,0,0,0,0,0,0}; A1 = A0; }

    f32x4 m0[2], m1[2];
    m0[0] = (f32x4){0,0,0,0}; m0[1] = m0[0]; m1[0] = m0[0]; m1[1] = m0[0];

    const short* bbase = (quad < 2) ? WtL : zslot;
    int bstride = (quad < 2) ? 1 : 0;

#pragma unroll 1
    for (int c4 = 0; c4 < 8; c4++) {
        f32x4 hv0[4], hv1[4];
#pragma unroll
        for (int r = 0; r < 4; r++) {
            hv0[r] = *(const f32x4*)&hsL[(t0 + quad * 4 + r) * 36 + c4 * 4];
            hv1[r] = *(const f32x4*)&hsL[(t1 + quad * 4 + r) * 36 + c4 * 4];
        }
#pragma unroll
        for (int cc = 0; cc < 4; cc++) {
            int c = c4 * 4 + cc;
#pragma unroll
            for (int oh = 0; oh < 2; oh++) {
                int cb = c * 2 + oh;
                bf16x8 B = *(const bf16x8*)&bbase[bstride * ((cb * 16 + n16) * 16 + quad * 8)];
                float bb = b_edge[(cb << 4) + n16];      // 4 KB table, L1-resident
                f32x4 Cb = (f32x4){bb, bb, bb, bb};
                f32x4 D0 = __builtin_amdgcn_mfma_f32_16x16x32_bf16(A0, B, Cb, 0, 0, 0);
                f32x4 D1 = __builtin_amdgcn_mfma_f32_16x16x32_bf16(A1, B, Cb, 0, 0, 0);
#pragma unroll
                for (int r = 0; r < 4; r++) {
                    m0[oh][r] = fmaf(hv0[r][cc], lrelu(D0[r]), m0[oh][r]);
                    m1[oh][r] = fmaf(hv1[r][cc], lrelu(D1[r]), m1[oh][r]);
                }
            }
        }
    }

#pragma unroll
    for (int r = 0; r < 4; r++) {
        int ed0 = dst[e0 + t0 + quad * 4 + r];
        int ed1 = dst[e0 + t1 + quad * 4 + r];
#pragma unroll
        for (int oh = 0; oh < 2; oh++) {
            unsafeAtomicAdd(&aggr[(size_t)ed0 * CH + oh * 16 + n16], m0[oh][r]);
            unsafeAtomicAdd(&aggr[(size_t)ed1 * CH + oh * 16 + n16], m1[oh][r]);
        }
    }
}

// ---------------- Kernel 3: out = leaky(aggr + h@W_root + b_conv) @ W_out + b_out
__global__ void k_node(const float* __restrict__ aggr,
                       const float* __restrict__ h,
                       const float* __restrict__ W_root,
                       const float* __restrict__ b_conv,
                       const float* __restrict__ W_out,
                       const float* __restrict__ b_out,
                       float* __restrict__ out) {
    __shared__ float WrT[CH * CH];   // transposed: WrT[o][c]
    __shared__ float Wo[CH];
    __shared__ float bc[CH];
    int tid = threadIdx.x;
#pragma unroll
    for (int i = 0; i < 4; i++) {
        int t = tid + 256 * i;       // t = o*32 + c
        WrT[t] = W_root[(t & 31) * CH + (t >> 5)];
    }
    if (tid < CH) { Wo[tid] = W_out[tid]; bc[tid] = b_conv[tid]; }
    __syncthreads();
    int n = blockIdx.x * 256 + tid;
    if (n >= NN) return;
    float hr[CH], ag[CH];
#pragma unroll
    for (int i = 0; i < CH / 4; i++) {
        ((float4*)hr)[i] = ((const float4*)(h + (size_t)n * CH))[i];
        ((float4*)ag)[i] = ((const float4*)(aggr + (size_t)n * CH))[i];
    }
    float acc = b_out[0];
#pragma unroll 1
    for (int o = 0; o < CH; o++) {
        float t = ag[o] + bc[o];
        const f32x4* wr = (const f32x4*)&WrT[o * CH];
#pragma unroll
        for (int c4 = 0; c4 < 8; c4++) {
            f32x4 w = wr[c4];
            const float* hc = &hr[c4 * 4];
            t = fmaf(hc[0], w[0], t); t = fmaf(hc[1], w[1], t);
            t = fmaf(hc[2], w[2], t); t = fmaf(hc[3], w[3], t);
        }
        acc = fmaf(lrelu(t), Wo[o], acc);
    }
    out[n] = acc;
}

extern "C" void kernel_launch(void* const* d_in, const int* in_sizes, int n_in,
                              void* d_out, int out_size, void* d_ws, size_t ws_size,
                              hipStream_t stream) {
    const float* x      = (const float*)d_in[0];
    const int*   ei     = (const int*)d_in[1];
    const float* ea     = (const float*)d_in[2];
    const float* W_in   = (const float*)d_in[3];
    const float* b_in   = (const float*)d_in[4];
    const float* W_edge = (const float*)d_in[5];
    const float* b_edge = (const float*)d_in[6];
    const float* W_root = (const float*)d_in[7];
    const float* b_conv = (const float*)d_in[8];
    const float* W_out  = (const float*)d_in[9];
    const float* b_out  = (const float*)d_in[10];
    float* out   = (float*)d_out;
    float* h     = (float*)d_ws;                 // [NN*CH] f32
    float* aggr  = h + (size_t)NN * CH;          // [NN*CH] f32
    short* WtT   = (short*)(aggr + (size_t)NN * CH);   // [1024*16] bf16
    short* ea_bf = WtT + 1024 * 16;              // [EE*16] bf16

    k_pre<<<PROJ_BLOCKS + AUX_BLOCKS, 256, 0, stream>>>(x, W_in, b_in, ea, W_edge,
                                                        h, aggr, WtT, ea_bf);
    k_edge<<<EE / 128, 256, 0, stream>>>(WtT, ea_bf, b_edge, ei, ei + EE, h, aggr);
    k_node<<<(NN + 255) / 256, 256, 0, stream>>>(aggr, h, W_root, b_conv, W_out, b_out, out);
}

// Round 4
// 189.178 us; speedup vs baseline: 1.1371x; 1.1371x over previous
//
#include <hip/hip_runtime.h>

#define NN 25000
#define EE 400000
#define FIN 128
#define FE 16
#define CH 32
#define SLOPE 0.01f
#define PROJ_BLOCKS 391   // ceil(25000/64)
#define AUX_BLOCKS 32
#define WROW 24                      // WtL row stride in shorts (48B = 16B-multiple)
#define WTP_SHORTS (1024 * WROW + 8) // +16B zero pad (quad-3 tail read)

typedef __attribute__((ext_vector_type(8))) short bf16x8;
typedef __attribute__((ext_vector_type(4))) float f32x4;

__device__ __forceinline__ float lrelu(float v) { return fmaxf(v, SLOPE * v); }

__device__ __forceinline__ f32x4 lrelu4(f32x4 v) {
    f32x4 s = v * SLOPE;             // 2x v_pk_mul_f32
    f32x4 r;
    r[0] = fmaxf(v[0], s[0]); r[1] = fmaxf(v[1], s[1]);
    r[2] = fmaxf(v[2], s[2]); r[3] = fmaxf(v[3], s[3]);
    return r;
}

// float -> bf16 bits, round-to-nearest-even
__device__ __forceinline__ short f2bf(float f) {
    union { float f; unsigned u; } v; v.f = f;
    unsigned r = (v.u + 0x7fffu + ((v.u >> 16) & 1u)) >> 16;
    return (short)r;
}

// ---------------- Kernel 1: fused prep
// blocks [0, PROJ_BLOCKS): h = leaky(x @ W_in + b_in) via MFMA (64 nodes/block)
// blocks [PROJ, +4): WtP[co][24] = {bf16 W_edge^T row, bias@16, zeros} ; [+4,+32): zero aggr
__global__ void __launch_bounds__(256)
k_pre(const float* __restrict__ x, const float* __restrict__ W_in,
      const float* __restrict__ b_in, const float* __restrict__ W_edge,
      const float* __restrict__ b_edge,
      float* __restrict__ h, float* __restrict__ aggr, short* __restrict__ WtP) {
    __shared__ short Wt1[CH * 136];
    int tid = threadIdx.x;

    if (blockIdx.x >= PROJ_BLOCKS) {
        int ab = blockIdx.x - PROJ_BLOCKS;
        if (ab < 4) {
            int co = ab * 256 + tid;                       // 0..1023
            short row[WROW] __attribute__((aligned(16)));
#pragma unroll
            for (int k = 0; k < 16; k++) row[k] = f2bf(W_edge[k * 1024 + co]);
            row[16] = f2bf(b_edge[co]);
#pragma unroll
            for (int k = 17; k < WROW; k++) row[k] = 0;
            uint4* dstp = (uint4*)(WtP + co * WROW);       // co*48B, 16B-aligned
            dstp[0] = ((uint4*)row)[0]; dstp[1] = ((uint4*)row)[1]; dstp[2] = ((uint4*)row)[2];
            if (ab == 0 && tid < 8) WtP[1024 * WROW + tid] = 0;   // tail pad
        } else {
            int t = (ab - 4) * 256 + tid;
            float4 z = make_float4(0.f, 0.f, 0.f, 0.f);
            for (int i = t; i < NN * CH / 4; i += (AUX_BLOCKS - 4) * 256)
                ((float4*)aggr)[i] = z;
        }
        return;
    }

    // ---- input projection ----
#pragma unroll
    for (int i = 0; i < 16; i++) {
        int id = tid + 256 * i;           // id = k*32 + c
        int k = id >> 5, c = id & 31;
        Wt1[c * 136 + k] = f2bf(W_in[id]);
    }
    __syncthreads();

    int wave = tid >> 6, lane = tid & 63;
    int n16 = lane & 15, quad = lane >> 4;
    int node0 = blockIdx.x * 64 + wave * 16;

    f32x4 D[2];
#pragma unroll
    for (int ch = 0; ch < 2; ch++) {
        float bb = b_in[ch * 16 + n16];
        D[ch] = (f32x4){bb, bb, bb, bb};
    }
    int arow = node0 + n16; if (arow >= NN) arow = NN - 1;
#pragma unroll
    for (int kb = 0; kb < 4; kb++) {
        const float4* xp = (const float4*)(x + (size_t)arow * FIN + kb * 32 + quad * 8);
        float4 xa = xp[0], xb = xp[1];
        bf16x8 A = (bf16x8){f2bf(xa.x), f2bf(xa.y), f2bf(xa.z), f2bf(xa.w),
                            f2bf(xb.x), f2bf(xb.y), f2bf(xb.z), f2bf(xb.w)};
#pragma unroll
        for (int ch = 0; ch < 2; ch++) {
            bf16x8 B = *(const bf16x8*)&Wt1[(ch * 16 + n16) * 136 + kb * 32 + quad * 8];
            D[ch] = __builtin_amdgcn_mfma_f32_16x16x32_bf16(A, B, D[ch], 0, 0, 0);
        }
    }
#pragma unroll
    for (int ch = 0; ch < 2; ch++)
#pragma unroll
        for (int r = 0; r < 4; r++) {
            int nn = node0 + quad * 4 + r;
            if (nn < NN) h[(size_t)nn * CH + ch * 16 + n16] = lrelu(D[ch][r]);
        }
}

// ---------------- Kernel 2: fused edge-NN (MFMA, bias folded in K-pad) + matvec + scatter
__global__ void __launch_bounds__(256, 2)
k_edge(const short* __restrict__ WtP,    // [1024][24] bf16 image (+pad)
       const float* __restrict__ ea,     // [EE][16] f32
       const int* __restrict__ src,
       const int* __restrict__ dst,
       const float* __restrict__ h,
       float* __restrict__ aggr) {
    __shared__ short WtL[WTP_SHORTS];    // 49168 B
    __shared__ float hsT[CH * 132];      // 16896 B, hsT[c][e], stride 132 (528B, 16B-mult)

    int tid = threadIdx.x;
    int e0 = blockIdx.x * 128;

    // stage WtL: 3073 uint4 vector copies
#pragma unroll
    for (int j = 0; j < 13; j++) {
        int idx = tid + 256 * j;
        if (idx < WTP_SHORTS / 8) ((uint4*)WtL)[idx] = ((const uint4*)WtP)[idx];
    }
    // stage hsT transposed: thread = (edge e=tid>>1, half=tid&1)
    {
        int e = tid >> 1, half = tid & 1;
        int s = src[e0 + e];
        const float4* hp = (const float4*)(h + (size_t)s * CH + half * 16);
        float vv[16] __attribute__((aligned(16)));
        *(float4*)&vv[0] = hp[0]; *(float4*)&vv[4] = hp[1];
        *(float4*)&vv[8] = hp[2]; *(float4*)&vv[12] = hp[3];
#pragma unroll
        for (int j = 0; j < 16; j++) hsT[(half * 16 + j) * 132 + e] = vv[j];
    }
    __syncthreads();

    int wave = tid >> 6, lane = tid & 63;
    int n16 = lane & 15, quad = lane >> 4;
    int t0 = wave * 32, t1 = t0 + 16;

    // A fragments: quads 0,1 = ea (f2bf in regs); quad 2 = {1.0, 0...} (bias row); quad 3 = 0
    bf16x8 A0 = (bf16x8){0,0,0,0,0,0,0,0}, A1 = A0;
    if (quad < 2) {
        const float4* p0 = (const float4*)(ea + (size_t)(e0 + t0 + n16) * FE + quad * 8);
        float4 a = p0[0], b = p0[1];
        A0 = (bf16x8){f2bf(a.x), f2bf(a.y), f2bf(a.z), f2bf(a.w),
                      f2bf(b.x), f2bf(b.y), f2bf(b.z), f2bf(b.w)};
        const float4* p1 = (const float4*)(ea + (size_t)(e0 + t1 + n16) * FE + quad * 8);
        a = p1[0]; b = p1[1];
        A1 = (bf16x8){f2bf(a.x), f2bf(a.y), f2bf(a.z), f2bf(a.w),
                      f2bf(b.x), f2bf(b.y), f2bf(b.z), f2bf(b.w)};
    } else if (quad == 2) {
        A0[0] = (short)0x3F80; A1[0] = (short)0x3F80;   // bf16 1.0 at k=16
    }

    f32x4 m0[2], m1[2];
    m0[0] = (f32x4){0,0,0,0}; m0[1] = m0[0]; m1[0] = m0[0]; m1[1] = m0[0];
    const f32x4 Z = (f32x4){0,0,0,0};

    // imm-offset bases
    const short* Bbase = WtL + n16 * WROW + quad * 8;    // + cb*16*WROW (imm)
    const float* h0b = hsT + t0 + quad * 4;              // + c*132 (imm)
    const float* h1b = hsT + t1 + quad * 4;

#pragma unroll 1
    for (int c4 = 0; c4 < 8; c4++) {
#pragma unroll
        for (int cc = 0; cc < 4; cc++) {
            int c = c4 * 4 + cc;
            f32x4 hc0 = *(const f32x4*)(h0b + c * 132);
            f32x4 hc1 = *(const f32x4*)(h1b + c * 132);
#pragma unroll
            for (int oh = 0; oh < 2; oh++) {
                int cb = c * 2 + oh;
                bf16x8 B = *(const bf16x8*)(Bbase + cb * (16 * WROW));
                f32x4 D0 = __builtin_amdgcn_mfma_f32_16x16x32_bf16(A0, B, Z, 0, 0, 0);
                f32x4 D1 = __builtin_amdgcn_mfma_f32_16x16x32_bf16(A1, B, Z, 0, 0, 0);
                m0[oh] += hc0 * lrelu4(D0);              // v_pk_fma_f32
                m1[oh] += hc1 * lrelu4(D1);
            }
        }
    }

    // scatter: lane holds msg for edges (tX + quad*4 + r), col o = oh*16 + n16
#pragma unroll
    for (int r = 0; r < 4; r++) {
        int ed0 = dst[e0 + t0 + quad * 4 + r];
        int ed1 = dst[e0 + t1 + quad * 4 + r];
#pragma unroll
        for (int oh = 0; oh < 2; oh++) {
            unsafeAtomicAdd(&aggr[(size_t)ed0 * CH + oh * 16 + n16], m0[oh][r]);
            unsafeAtomicAdd(&aggr[(size_t)ed1 * CH + oh * 16 + n16], m1[oh][r]);
        }
    }
}

// ---------------- Kernel 3: out = leaky(aggr + h@W_root + b_conv) @ W_out + b_out
__global__ void k_node(const float* __restrict__ aggr,
                       const float* __restrict__ h,
                       const float* __restrict__ W_root,
                       const float* __restrict__ b_conv,
                       const float* __restrict__ W_out,
                       const float* __restrict__ b_out,
                       float* __restrict__ out) {
    __shared__ float WrT[CH * CH];   // transposed: WrT[o][c]
    __shared__ float Wo[CH];
    __shared__ float bc[CH];
    int tid = threadIdx.x;
#pragma unroll
    for (int i = 0; i < 4; i++) {
        int t = tid + 256 * i;       // t = o*32 + c
        WrT[t] = W_root[(t & 31) * CH + (t >> 5)];
    }
    if (tid < CH) { Wo[tid] = W_out[tid]; bc[tid] = b_conv[tid]; }
    __syncthreads();
    int n = blockIdx.x * 256 + tid;
    if (n >= NN) return;
    float hr[CH], ag[CH];
#pragma unroll
    for (int i = 0; i < CH / 4; i++) {
        ((float4*)hr)[i] = ((const float4*)(h + (size_t)n * CH))[i];
        ((float4*)ag)[i] = ((const float4*)(aggr + (size_t)n * CH))[i];
    }
    float acc = b_out[0];
#pragma unroll 1
    for (int o = 0; o < CH; o++) {
        float t = ag[o] + bc[o];
        const f32x4* wr = (const f32x4*)&WrT[o * CH];
#pragma unroll
        for (int c4 = 0; c4 < 8; c4++) {
            f32x4 w = wr[c4];
            const float* hc = &hr[c4 * 4];
            t = fmaf(hc[0], w[0], t); t = fmaf(hc[1], w[1], t);
            t = fmaf(hc[2], w[2], t); t = fmaf(hc[3], w[3], t);
        }
        acc = fmaf(lrelu(t), Wo[o], acc);
    }
    out[n] = acc;
}

extern "C" void kernel_launch(void* const* d_in, const int* in_sizes, int n_in,
                              void* d_out, int out_size, void* d_ws, size_t ws_size,
                              hipStream_t stream) {
    const float* x      = (const float*)d_in[0];
    const int*   ei     = (const int*)d_in[1];
    const float* ea     = (const float*)d_in[2];
    const float* W_in   = (const float*)d_in[3];
    const float* b_in   = (const float*)d_in[4];
    const float* W_edge = (const float*)d_in[5];
    const float* b_edge = (const float*)d_in[6];
    const float* W_root = (const float*)d_in[7];
    const float* b_conv = (const float*)d_in[8];
    const float* W_out  = (const float*)d_in[9];
    const float* b_out  = (const float*)d_in[10];
    float* out  = (float*)d_out;
    float* h    = (float*)d_ws;                  // [NN*CH] f32
    float* aggr = h + (size_t)NN * CH;           // [NN*CH] f32
    short* WtP  = (short*)(aggr + (size_t)NN * CH);  // [WTP_SHORTS] bf16 image

    k_pre<<<PROJ_BLOCKS + AUX_BLOCKS, 256, 0, stream>>>(x, W_in, b_in, W_edge, b_edge,
                                                        h, aggr, WtP);
    k_edge<<<EE / 128, 256, 0, stream>>>(WtP, ea, ei, ei + EE, h, aggr);
    k_node<<<(NN + 255) / 256, 256, 0, stream>>>(aggr, h, W_root, b_conv, W_out, b_out, out);
}

// Round 5
// 167.248 us; speedup vs baseline: 1.2862x; 1.1311x over previous
//
#include <hip/hip_runtime.h>

#define NN 25000
#define EE 400000
#define FIN 128
#define FE 16
#define CH 32
#define SLOPE 0.01f
#define PROJ_BLOCKS 391   // ceil(25000/64)
#define AUX_BLOCKS 32
#define WROW 24                      // WtL row stride in shorts (48B = 16B-multiple)
#define WTP_SHORTS (1024 * WROW + 8) // +16B zero pad (quad-3 tail read)

typedef __attribute__((ext_vector_type(8))) short bf16x8;
typedef __attribute__((ext_vector_type(4))) float f32x4;

__device__ __forceinline__ float lrelu(float v) { return fmaxf(v, SLOPE * v); }

__device__ __forceinline__ f32x4 lrelu4(f32x4 v) {
    f32x4 s = v * SLOPE;
#if __has_builtin(__builtin_elementwise_max)
    return __builtin_elementwise_max(v, s);   // v_pk_max_f32
#else
    f32x4 r;
    r[0] = fmaxf(v[0], s[0]); r[1] = fmaxf(v[1], s[1]);
    r[2] = fmaxf(v[2], s[2]); r[3] = fmaxf(v[3], s[3]);
    return r;
#endif
}

// float -> bf16 bits, round-to-nearest-even
__device__ __forceinline__ short f2bf(float f) {
    union { float f; unsigned u; } v; v.f = f;
    unsigned r = (v.u + 0x7fffu + ((v.u >> 16) & 1u)) >> 16;
    return (short)r;
}

// ---------------- Kernel 1: fused prep
// blocks [0, PROJ_BLOCKS): h = leaky(x @ W_in + b_in) via MFMA (64 nodes/block)
// blocks [PROJ, +4): WtP[co][24] = {bf16 W_edge^T row, bias@16, zeros} ; [+4,+32): zero aggr
__global__ void __launch_bounds__(256)
k_pre(const float* __restrict__ x, const float* __restrict__ W_in,
      const float* __restrict__ b_in, const float* __restrict__ W_edge,
      const float* __restrict__ b_edge,
      float* __restrict__ h, float* __restrict__ aggr, short* __restrict__ WtP) {
    __shared__ short Wt1[CH * 136];
    int tid = threadIdx.x;

    if (blockIdx.x >= PROJ_BLOCKS) {
        int ab = blockIdx.x - PROJ_BLOCKS;
        if (ab < 4) {
            int co = ab * 256 + tid;                       // 0..1023
            short row[WROW] __attribute__((aligned(16)));
#pragma unroll
            for (int k = 0; k < 16; k++) row[k] = f2bf(W_edge[k * 1024 + co]);
            row[16] = f2bf(b_edge[co]);
#pragma unroll
            for (int k = 17; k < WROW; k++) row[k] = 0;
            uint4* dstp = (uint4*)(WtP + co * WROW);       // co*48B, 16B-aligned
            dstp[0] = ((uint4*)row)[0]; dstp[1] = ((uint4*)row)[1]; dstp[2] = ((uint4*)row)[2];
            if (ab == 0 && tid < 8) WtP[1024 * WROW + tid] = 0;   // tail pad
        } else {
            int t = (ab - 4) * 256 + tid;
            float4 z = make_float4(0.f, 0.f, 0.f, 0.f);
            for (int i = t; i < NN * CH / 4; i += (AUX_BLOCKS - 4) * 256)
                ((float4*)aggr)[i] = z;
        }
        return;
    }

    // ---- input projection ----
#pragma unroll
    for (int i = 0; i < 16; i++) {
        int id = tid + 256 * i;           // id = k*32 + c
        int k = id >> 5, c = id & 31;
        Wt1[c * 136 + k] = f2bf(W_in[id]);
    }
    __syncthreads();

    int wave = tid >> 6, lane = tid & 63;
    int n16 = lane & 15, quad = lane >> 4;
    int node0 = blockIdx.x * 64 + wave * 16;

    f32x4 D[2];
#pragma unroll
    for (int ch = 0; ch < 2; ch++) {
        float bb = b_in[ch * 16 + n16];
        D[ch] = (f32x4){bb, bb, bb, bb};
    }
    int arow = node0 + n16; if (arow >= NN) arow = NN - 1;
#pragma unroll
    for (int kb = 0; kb < 4; kb++) {
        const float4* xp = (const float4*)(x + (size_t)arow * FIN + kb * 32 + quad * 8);
        float4 xa = xp[0], xb = xp[1];
        bf16x8 A = (bf16x8){f2bf(xa.x), f2bf(xa.y), f2bf(xa.z), f2bf(xa.w),
                            f2bf(xb.x), f2bf(xb.y), f2bf(xb.z), f2bf(xb.w)};
#pragma unroll
        for (int ch = 0; ch < 2; ch++) {
            bf16x8 B = *(const bf16x8*)&Wt1[(ch * 16 + n16) * 136 + kb * 32 + quad * 8];
            D[ch] = __builtin_amdgcn_mfma_f32_16x16x32_bf16(A, B, D[ch], 0, 0, 0);
        }
    }
#pragma unroll
    for (int ch = 0; ch < 2; ch++)
#pragma unroll
        for (int r = 0; r < 4; r++) {
            int nn = node0 + quad * 4 + r;
            if (nn < NN) h[(size_t)nn * CH + ch * 16 + n16] = lrelu(D[ch][r]);
        }
}

// ---------------- Kernel 2: fused edge-NN (MFMA, bias folded in K-pad) + matvec + scatter
__global__ void __launch_bounds__(256, 2)
k_edge(const short* __restrict__ WtP,    // [1024][24] bf16 image (+pad)
       const float* __restrict__ ea,     // [EE][16] f32
       const int* __restrict__ src,
       const int* __restrict__ dst,
       const float* __restrict__ h,
       float* __restrict__ aggr) {
    __shared__ short WtL[WTP_SHORTS];    // 49168 B
    __shared__ float hsT[CH * 132];      // 16896 B, hsT[c][e], stride 132

    int tid = threadIdx.x;
    int e0 = blockIdx.x * 128;

    // stage WtL: 3073 uint4 vector copies
#pragma unroll
    for (int j = 0; j < 13; j++) {
        int idx = tid + 256 * j;
        if (idx < WTP_SHORTS / 8) ((uint4*)WtL)[idx] = ((const uint4*)WtP)[idx];
    }
    // stage hsT transposed: thread = (edge e=tid>>1, half=tid&1)
    {
        int e = tid >> 1, half = tid & 1;
        int s = src[e0 + e];
        const float4* hp = (const float4*)(h + (size_t)s * CH + half * 16);
        float vv[16] __attribute__((aligned(16)));
        *(float4*)&vv[0] = hp[0]; *(float4*)&vv[4] = hp[1];
        *(float4*)&vv[8] = hp[2]; *(float4*)&vv[12] = hp[3];
#pragma unroll
        for (int j = 0; j < 16; j++) hsT[(half * 16 + j) * 132 + e] = vv[j];
    }
    __syncthreads();

    int wave = tid >> 6, lane = tid & 63;
    int n16 = lane & 15, quad = lane >> 4;
    int t0 = wave * 32, t1 = t0 + 16;

    // A fragments: quads 0,1 = ea (f2bf in regs); quad 2 = {1.0, 0...} (bias row); quad 3 = 0
    bf16x8 A0 = (bf16x8){0,0,0,0,0,0,0,0}, A1 = A0;
    if (quad < 2) {
        const float4* p0 = (const float4*)(ea + (size_t)(e0 + t0 + n16) * FE + quad * 8);
        float4 a = p0[0], b = p0[1];
        A0 = (bf16x8){f2bf(a.x), f2bf(a.y), f2bf(a.z), f2bf(a.w),
                      f2bf(b.x), f2bf(b.y), f2bf(b.z), f2bf(b.w)};
        const float4* p1 = (const float4*)(ea + (size_t)(e0 + t1 + n16) * FE + quad * 8);
        a = p1[0]; b = p1[1];
        A1 = (bf16x8){f2bf(a.x), f2bf(a.y), f2bf(a.z), f2bf(a.w),
                      f2bf(b.x), f2bf(b.y), f2bf(b.z), f2bf(b.w)};
    } else if (quad == 2) {
        A0[0] = (short)0x3F80; A1[0] = (short)0x3F80;   // bf16 1.0 at k=16
    }

    f32x4 m0[2], m1[2];
    m0[0] = (f32x4){0,0,0,0}; m0[1] = m0[0]; m1[0] = m0[0]; m1[1] = m0[0];
    const f32x4 Z = (f32x4){0,0,0,0};

    // imm-offset bases
    const short* Bbase = WtL + n16 * WROW + quad * 8;    // + cb*16*WROW (imm)
    const float* h0b = hsT + t0 + quad * 4;              // + c*132 (imm)
    const float* h1b = hsT + t1 + quad * 4;

#pragma unroll
    for (int c4 = 0; c4 < 8; c4++) {
#pragma unroll
        for (int cc = 0; cc < 4; cc++) {
            int c = c4 * 4 + cc;
            f32x4 hc0 = *(const f32x4*)(h0b + c * 132);
            f32x4 hc1 = *(const f32x4*)(h1b + c * 132);
#pragma unroll
            for (int oh = 0; oh < 2; oh++) {
                int cb = c * 2 + oh;
                bf16x8 B = *(const bf16x8*)(Bbase + cb * (16 * WROW));
                f32x4 D0 = __builtin_amdgcn_mfma_f32_16x16x32_bf16(A0, B, Z, 0, 0, 0);
                f32x4 D1 = __builtin_amdgcn_mfma_f32_16x16x32_bf16(A1, B, Z, 0, 0, 0);
                m0[oh] += hc0 * lrelu4(D0);              // v_pk_fma_f32
                m1[oh] += hc1 * lrelu4(D1);
            }
        }
    }

    // scatter: lane holds msg for edges (tX + quad*4 + r), col o = oh*16 + n16
#pragma unroll
    for (int r = 0; r < 4; r++) {
        int ed0 = dst[e0 + t0 + quad * 4 + r];
        int ed1 = dst[e0 + t1 + quad * 4 + r];
#pragma unroll
        for (int oh = 0; oh < 2; oh++) {
            unsafeAtomicAdd(&aggr[(size_t)ed0 * CH + oh * 16 + n16], m0[oh][r]);
            unsafeAtomicAdd(&aggr[(size_t)ed1 * CH + oh * 16 + n16], m1[oh][r]);
        }
    }
}

// ---------------- Kernel 3 (MFMA): out = leaky(aggr + h@W_root + b_conv) @ W_out + b_out
// Wave = 16 nodes. A = h rows (K=32 exact). C = aggr + b_conv. 2 MFMAs (o 0..15, 16..31).
__global__ void __launch_bounds__(256)
k_node(const float* __restrict__ aggr,
       const float* __restrict__ h,
       const float* __restrict__ W_root,
       const float* __restrict__ b_conv,
       const float* __restrict__ W_out,
       const float* __restrict__ b_out,
       float* __restrict__ out) {
    __shared__ short WrB[CH * 40];   // W_root^T bf16: [o][c], stride 40 shorts (80B)
    __shared__ float WoS[CH];
    int tid = threadIdx.x;
    if (tid < 128) {
        int o = tid >> 2, c0 = (tid & 3) * 8;
        short tmp[8] __attribute__((aligned(16)));
#pragma unroll
        for (int j = 0; j < 8; j++) tmp[j] = f2bf(W_root[(c0 + j) * CH + o]);
        *(bf16x8*)&WrB[o * 40 + c0] = *(bf16x8*)tmp;
    } else if (tid < 160) {
        WoS[tid - 128] = W_out[tid - 128];
    }
    __syncthreads();

    int wave = tid >> 6, lane = tid & 63;
    int n16 = lane & 15, quad = lane >> 4;
    int node0 = blockIdx.x * 64 + wave * 16;

    // A: row m=n16 of h (clamped), k = quad*8..+7
    int arow = node0 + n16; if (arow >= NN) arow = NN - 1;
    const float4* hp = (const float4*)(h + (size_t)arow * CH + quad * 8);
    float4 ha = hp[0], hb = hp[1];
    bf16x8 A = (bf16x8){f2bf(ha.x), f2bf(ha.y), f2bf(ha.z), f2bf(ha.w),
                        f2bf(hb.x), f2bf(hb.y), f2bf(hb.z), f2bf(hb.w)};
    // C: aggr + b_conv for rows quad*4+r, cols n16 / 16+n16
    float bc0 = b_conv[n16], bc1 = b_conv[16 + n16];
    f32x4 C0, C1;
#pragma unroll
    for (int r = 0; r < 4; r++) {
        int nr = node0 + quad * 4 + r; int cr = (nr < NN) ? nr : NN - 1;
        C0[r] = aggr[(size_t)cr * CH + n16] + bc0;
        C1[r] = aggr[(size_t)cr * CH + 16 + n16] + bc1;
    }
    bf16x8 B0 = *(const bf16x8*)&WrB[n16 * 40 + quad * 8];
    bf16x8 B1 = *(const bf16x8*)&WrB[(16 + n16) * 40 + quad * 8];
    f32x4 D0 = __builtin_amdgcn_mfma_f32_16x16x32_bf16(A, B0, C0, 0, 0, 0);
    f32x4 D1 = __builtin_amdgcn_mfma_f32_16x16x32_bf16(A, B1, C1, 0, 0, 0);

    // p[r] = lrelu(D0[r])*Wo[n16] + lrelu(D1[r])*Wo[16+n16]; reduce over n16
    float w0 = WoS[n16], w1 = WoS[16 + n16];
    f32x4 p;
#pragma unroll
    for (int r = 0; r < 4; r++)
        p[r] = lrelu(D0[r]) * w0 + lrelu(D1[r]) * w1;
#pragma unroll
    for (int mk = 1; mk < 16; mk <<= 1) {
#pragma unroll
        for (int r = 0; r < 4; r++) p[r] += __shfl_xor(p[r], mk, 64);
    }
    if (n16 == 0) {
        float bo = b_out[0];
#pragma unroll
        for (int r = 0; r < 4; r++) {
            int nr = node0 + quad * 4 + r;
            if (nr < NN) out[nr] = p[r] + bo;
        }
    }
}

extern "C" void kernel_launch(void* const* d_in, const int* in_sizes, int n_in,
                              void* d_out, int out_size, void* d_ws, size_t ws_size,
                              hipStream_t stream) {
    const float* x      = (const float*)d_in[0];
    const int*   ei     = (const int*)d_in[1];
    const float* ea     = (const float*)d_in[2];
    const float* W_in   = (const float*)d_in[3];
    const float* b_in   = (const float*)d_in[4];
    const float* W_edge = (const float*)d_in[5];
    const float* b_edge = (const float*)d_in[6];
    const float* W_root = (const float*)d_in[7];
    const float* b_conv = (const float*)d_in[8];
    const float* W_out  = (const float*)d_in[9];
    const float* b_out  = (const float*)d_in[10];
    float* out  = (float*)d_out;
    float* h    = (float*)d_ws;                  // [NN*CH] f32
    float* aggr = h + (size_t)NN * CH;           // [NN*CH] f32
    short* WtP  = (short*)(aggr + (size_t)NN * CH);  // [WTP_SHORTS] bf16 image

    k_pre<<<PROJ_BLOCKS + AUX_BLOCKS, 256, 0, stream>>>(x, W_in, b_in, W_edge, b_edge,
                                                        h, aggr, WtP);
    k_edge<<<EE / 128, 256, 0, stream>>>(WtP, ea, ei, ei + EE, h, aggr);
    k_node<<<PROJ_BLOCKS, 256, 0, stream>>>(aggr, h, W_root, b_conv, W_out, b_out, out);
}